// Round 6
// baseline (155.624 us; speedup 1.0000x reference)
//
#include <hip/hip_runtime.h>
#include <hip/hip_bf16.h>
#include <math.h>

#define NQ 9
#define NL 10
#define DIM 512
#define NCLS 10
#define B_TOT 16384

// ws layout (bytes): A bf16 [16384x512] @ 0 (16MB); BT bf16 [1024x512] @ 16MB;
// Zp f32 [4][16384][10] @ 32MB (2.62MB); gate table f32[900] @ 48MB.
// NOTE (R13 lesson): bulk data between workgroups of ONE launch is unsafe on
// CDNA4 (per-XCD L2 non-coherent) — all producer->consumer crossings here are
// kernel boundaries (gates->prep, prep->gemm, gemm->zred).
#define A_OFF   ((size_t)0)
#define BT_OFF  ((size_t)16 << 20)
#define ZP_OFF  ((size_t)32 << 20)
#define GT_OFF  ((size_t)48 << 20)
#define WS_NEED (((size_t)96) << 20)

#if __has_builtin(__builtin_amdgcn_permlane16_swap) && __has_builtin(__builtin_amdgcn_permlane32_swap)
#define HAS_PL 1
#else
#define HAS_PL 0
#endif
typedef int iv2 __attribute__((ext_vector_type(2)));

__device__ __forceinline__ float shx(float v, int m) { return __shfl_xor(v, m, 64); }

// ---- VALU lane-XOR permutes. DPP ctrls: quad_perm<=0xFF, row_ror:8=0x128,
// ---- row_half_mirror=0x141. XOR4 = quad[3,2,1,0](i^3) o half_mirror(i^7).
template<int CTRL>
__device__ __forceinline__ float dppq(float v) {
  return __int_as_float(__builtin_amdgcn_update_dpp(
      0, __float_as_int(v), CTRL, 0xF, 0xF, true));
}

// permlane{16,32}_swap with both inputs = v: one output half-broadcasts lo,
// the other hi; partner(lane^M) = select on the lane bit. A wrong
// element-order assumption degenerates to identity -> runtime self-test.
template<int M, bool PL>
__device__ __forceinline__ float shxt(float v) {
  if constexpr (M == 1)       return dppq<0xB1>(v);
  else if constexpr (M == 2)  return dppq<0x4E>(v);
  else if constexpr (M == 4)  return dppq<0x1B>(dppq<0x141>(v));
  else if constexpr (M == 8)  return dppq<0x128>(v);
  else if constexpr (M == 16) {
#if HAS_PL
    if constexpr (PL) {
      iv2 r = __builtin_amdgcn_permlane16_swap(__float_as_int(v), __float_as_int(v),
                                               false, false);
      return __int_as_float((threadIdx.x & 16) ? r.x : r.y);
    }
#endif
    return shx(v, 16);
  } else {
#if HAS_PL
    if constexpr (PL) {
      iv2 r = __builtin_amdgcn_permlane32_swap(__float_as_int(v), __float_as_int(v),
                                               false, false);
      return __int_as_float((threadIdx.x & 32) ? r.x : r.y);
    }
#endif
    return shx(v, 32);
  }
}

__device__ __forceinline__ int looks_bf16(const void* p, int count) {
  const unsigned short* u = (const unsigned short*)p;
  int n = count < 64 ? count : 64;
  int good = 0;
  for (int i = 0; i < n; ++i) {
    unsigned short v = u[i];
    int e = (v >> 7) & 0xFF;
    good += (e >= 100 && e <= 140) || ((v & 0x7FFF) == 0);
  }
  return good * 8 >= n * 7;
}

__device__ __forceinline__ float ld(const void* p, int i, int isbf) {
  if (isbf) return __uint_as_float(((unsigned)((const unsigned short*)p)[i]) << 16);
  return ((const float*)p)[i];
}

// ---------------- 8-amp gate helpers (verified R3; used by fallback) -------
template<int M>
__device__ __forceinline__ void rot_x(float (&sr)[8], float (&si)[8], const float* u) {
  float4 uA = *(const float4*)u;
  float4 uB = *(const float4*)(u + 4);
  bool hi = (threadIdx.x & M) != 0;
  float ar = hi ? uB.z : uA.x, ai = hi ? uB.w : uA.y;
  float br = hi ? uB.x : uA.z, bi = hi ? uB.y : uA.w;
#pragma unroll
  for (int r = 0; r < 8; ++r) {
    float pr = shx(sr[r], M), pi = shx(si[r], M);
    float nr = ar * sr[r] - ai * si[r] + br * pr - bi * pi;
    float ni = ar * si[r] + ai * sr[r] + br * pi + bi * pr;
    sr[r] = nr; si[r] = ni;
  }
}
template<int S>
__device__ __forceinline__ void rot_r(float (&sr)[8], float (&si)[8], const float* u) {
  float4 uA = *(const float4*)u;
  float4 uB = *(const float4*)(u + 4);
#pragma unroll
  for (int r0 = 0; r0 < 8; ++r0) {
    if (r0 & S) continue;
    int r1 = r0 + S;
    float a0r = sr[r0], a0i = si[r0], a1r = sr[r1], a1i = si[r1];
    sr[r0] = uA.x * a0r - uA.y * a0i + uA.z * a1r - uA.w * a1i;
    si[r0] = uA.x * a0i + uA.y * a0r + uA.z * a1i + uA.w * a1r;
    sr[r1] = uB.x * a0r - uB.y * a0i + uB.z * a1r - uB.w * a1i;
    si[r1] = uB.x * a0i + uB.y * a0r + uB.z * a1i + uB.w * a1r;
  }
}
template<int MC, int MT>
__device__ __forceinline__ void crx_ll(float (&sr)[8], float (&si)[8], const float* cs) {
  bool ctrl = (threadIdx.x & MC) != 0;
  float c = ctrl ? cs[0] : 1.0f;
  float s = ctrl ? cs[1] : 0.0f;
#pragma unroll
  for (int r = 0; r < 8; ++r) {
    float pr = shx(sr[r], MT), pi = shx(si[r], MT);
    float nr = c * sr[r] + s * pi;
    float ni = c * si[r] - s * pr;
    sr[r] = nr; si[r] = ni;
  }
}
template<int MC, int ST>
__device__ __forceinline__ void crx_lr(float (&sr)[8], float (&si)[8], const float* cs) {
  bool ctrl = (threadIdx.x & MC) != 0;
  float c = ctrl ? cs[0] : 1.0f;
  float s = ctrl ? cs[1] : 0.0f;
#pragma unroll
  for (int r0 = 0; r0 < 8; ++r0) {
    if (r0 & ST) continue;
    int r1 = r0 + ST;
    float a0r = sr[r0], a0i = si[r0], a1r = sr[r1], a1i = si[r1];
    sr[r0] = c * a0r + s * a1i;  si[r0] = c * a0i - s * a1r;
    sr[r1] = c * a1r + s * a0i;  si[r1] = c * a1i - s * a0r;
  }
}
template<int PC, int ST>
__device__ __forceinline__ void crx_rr(float (&sr)[8], float (&si)[8], const float* cs) {
  float c = cs[0], s = cs[1];
#pragma unroll
  for (int r0 = 0; r0 < 8; ++r0) {
    if (r0 & ST) continue;
    if (!((r0 >> PC) & 1)) continue;
    int r1 = r0 + ST;
    float a0r = sr[r0], a0i = si[r0], a1r = sr[r1], a1i = si[r1];
    sr[r0] = c * a0r + s * a1i;  si[r0] = c * a0i - s * a1r;
    sr[r1] = c * a1r + s * a0i;  si[r1] = c * a1i - s * a0r;
  }
}
template<int PC, int MT>
__device__ __forceinline__ void crx_rl(float (&sr)[8], float (&si)[8], const float* cs) {
  float c = cs[0], s = cs[1];
#pragma unroll
  for (int r = 0; r < 8; ++r) {
    if (!((r >> PC) & 1)) continue;
    float pr = shx(sr[r], MT), pi = shx(si[r], MT);
    float nr = c * sr[r] + s * pi;
    float ni = c * si[r] - s * pr;
    sr[r] = nr; si[r] = ni;
  }
}

// -------- VALU-shuffle gate variants (batched; no lgkmcnt in the circuit) --
template<int M, bool PL>
__device__ __forceinline__ void rot_xb(float (&sr)[8], float (&si)[8], const float* u) {
  float4 uA = *(const float4*)u;
  float4 uB = *(const float4*)(u + 4);
  bool hi = (threadIdx.x & M) != 0;
  float ar = hi ? uB.z : uA.x, ai = hi ? uB.w : uA.y;
  float br = hi ? uB.x : uA.z, bi = hi ? uB.y : uA.w;
  float pr[8], pi[8];
#pragma unroll
  for (int r = 0; r < 8; ++r) { pr[r] = shxt<M, PL>(sr[r]); pi[r] = shxt<M, PL>(si[r]); }
#pragma unroll
  for (int r = 0; r < 8; ++r) {
    float nr = ar * sr[r] - ai * si[r] + br * pr[r] - bi * pi[r];
    float ni = ar * si[r] + ai * sr[r] + br * pi[r] + bi * pr[r];
    sr[r] = nr; si[r] = ni;
  }
}
template<int MC, int MT, bool PL>
__device__ __forceinline__ void crx_llb(float (&sr)[8], float (&si)[8], const float* cs) {
  bool ctrl = (threadIdx.x & MC) != 0;
  float c = ctrl ? cs[0] : 1.0f;
  float s = ctrl ? cs[1] : 0.0f;
  float pr[8], pi[8];
#pragma unroll
  for (int r = 0; r < 8; ++r) { pr[r] = shxt<MT, PL>(sr[r]); pi[r] = shxt<MT, PL>(si[r]); }
#pragma unroll
  for (int r = 0; r < 8; ++r) {
    float nr = c * sr[r] + s * pi[r];
    float ni = c * si[r] - s * pr[r];
    sr[r] = nr; si[r] = ni;
  }
}
// crx_rl<0,32>: odd regs only, target mask 32
template<bool PL>
__device__ __forceinline__ void crx_rlb032(float (&sr)[8], float (&si)[8], const float* cs) {
  float c = cs[0], s = cs[1];
  float pr[4], pi[4];
#pragma unroll
  for (int t = 0; t < 4; ++t) {
    int r = 2 * t + 1;
    pr[t] = shxt<32, PL>(sr[r]); pi[t] = shxt<32, PL>(si[r]);
  }
#pragma unroll
  for (int t = 0; t < 4; ++t) {
    int r = 2 * t + 1;
    float nr = c * sr[r] + s * pi[t];
    float ni = c * si[r] - s * pr[t];
    sr[r] = nr; si[r] = ni;
  }
}

__device__ __forceinline__ void build_gates(const void* rot, const void* crx,
                                            float* gU, float* gCS) {
  int tid = threadIdx.x;
  __shared__ int gflags[2];
  if (tid == 0) {
    gflags[0] = looks_bf16(rot, NL * NQ * 3);
    gflags[1] = looks_bf16(crx, NL * NQ);
  }
  __syncthreads();
  if (tid < NL * NQ) {
    int frot = gflags[0], fcrx = gflags[1];
    float phi = ld(rot, tid * 3 + 0, frot);
    float th  = ld(rot, tid * 3 + 1, frot);
    float om  = ld(rot, tid * 3 + 2, frot);
    float c = cosf(0.5f * th), s = sinf(0.5f * th);
    float a = 0.5f * (phi + om), b = 0.5f * (phi - om);
    float ca = cosf(a), sa = sinf(a), cb = cosf(b), sb = sinf(b);
    float* u = gU + tid * 8;
    u[0] =  ca * c; u[1] = -sa * c;
    u[2] = -cb * s; u[3] = -sb * s;
    u[4] =  cb * s; u[5] = -sb * s;
    u[6] =  ca * c; u[7] =  sa * c;
    float t2 = 0.5f * ld(crx, tid, fcrx);
    gCS[tid * 2 + 0] = cosf(t2);
    gCS[tid * 2 + 1] = sinf(t2);
  }
  __syncthreads();
}

__device__ __forceinline__ void run_circuit(float (&sr)[8], float (&si)[8],
                                            const float* gU, const float* gCS) {
#pragma unroll 1
  for (int n = 0; n < NL; ++n) {
    const float* U  = gU  + n * NQ * 8;
    const float* CS = gCS + n * NQ * 2;
    rot_x<32>(sr, si, U + 0 * 8);
    rot_x<16>(sr, si, U + 1 * 8);
    rot_x< 8>(sr, si, U + 2 * 8);
    rot_x< 4>(sr, si, U + 3 * 8);
    rot_x< 2>(sr, si, U + 4 * 8);
    rot_x< 1>(sr, si, U + 5 * 8);
    rot_r< 4>(sr, si, U + 6 * 8);
    rot_r< 2>(sr, si, U + 7 * 8);
    rot_r< 1>(sr, si, U + 8 * 8);
    crx_ll<32, 16>(sr, si, CS + 0 * 2);
    crx_ll<16,  8>(sr, si, CS + 1 * 2);
    crx_ll< 8,  4>(sr, si, CS + 2 * 2);
    crx_ll< 4,  2>(sr, si, CS + 3 * 2);
    crx_ll< 2,  1>(sr, si, CS + 4 * 2);
    crx_lr< 1,  4>(sr, si, CS + 5 * 2);
    crx_rr< 2,  2>(sr, si, CS + 6 * 2);
    crx_rr< 1,  1>(sr, si, CS + 7 * 2);
    crx_rl< 0, 32>(sr, si, CS + 8 * 2);
  }
}

// all-VALU-shuffle version; gU/gCS are GLOBAL wave-uniform pointers -> the
// compiler emits s_load (scalar cache, 3.6KB table) — no LDS / no lgkmcnt
// on the gate-constant path (R5 post-mortem: per-gate LDS const reads were
// the surviving serial stall).
template<bool PL>
__device__ __forceinline__ void run_circuit_v(float (&sr)[8], float (&si)[8],
                                              const float* __restrict__ gU,
                                              const float* __restrict__ gCS) {
#pragma unroll 1
  for (int n = 0; n < NL; ++n) {
    const float* U  = gU  + n * NQ * 8;
    const float* CS = gCS + n * NQ * 2;
    rot_xb<32, PL>(sr, si, U + 0 * 8);
    rot_xb<16, PL>(sr, si, U + 1 * 8);
    rot_xb< 8, PL>(sr, si, U + 2 * 8);
    rot_xb< 4, PL>(sr, si, U + 3 * 8);
    rot_xb< 2, PL>(sr, si, U + 4 * 8);
    rot_xb< 1, PL>(sr, si, U + 5 * 8);
    rot_r< 4>(sr, si, U + 6 * 8);
    rot_r< 2>(sr, si, U + 7 * 8);
    rot_r< 1>(sr, si, U + 8 * 8);
    crx_llb<32, 16, PL>(sr, si, CS + 0 * 2);
    crx_llb<16,  8, PL>(sr, si, CS + 1 * 2);
    crx_llb< 8,  4, PL>(sr, si, CS + 2 * 2);
    crx_llb< 4,  2, PL>(sr, si, CS + 3 * 2);
    crx_llb< 2,  1, PL>(sr, si, CS + 4 * 2);
    crx_lr< 1,  4>(sr, si, CS + 5 * 2);
    crx_rr< 2,  2>(sr, si, CS + 6 * 2);
    crx_rr< 1,  1>(sr, si, CS + 7 * 2);
    crx_rlb032<PL>(sr, si, CS + 8 * 2);
  }
}

// -------- gates precompute: 1 block writes the 900-float table to global ---
__global__ __launch_bounds__(128) void gates_kernel(const void* __restrict__ rot,
                                                    const void* __restrict__ crx,
                                                    float* __restrict__ gG) {
  int tid = threadIdx.x;
  __shared__ int gflags[2];
  if (tid == 0) {
    gflags[0] = looks_bf16(rot, NL * NQ * 3);
    gflags[1] = looks_bf16(crx, NL * NQ);
  }
  __syncthreads();
  if (tid < NL * NQ) {
    int frot = gflags[0], fcrx = gflags[1];
    float phi = ld(rot, tid * 3 + 0, frot);
    float th  = ld(rot, tid * 3 + 1, frot);
    float om  = ld(rot, tid * 3 + 2, frot);
    float c = cosf(0.5f * th), s = sinf(0.5f * th);
    float a = 0.5f * (phi + om), b = 0.5f * (phi - om);
    float ca = cosf(a), sa = sinf(a), cb = cosf(b), sb = sinf(b);
    float* u = gG + tid * 8;                       // gU region [0, 720)
    u[0] =  ca * c; u[1] = -sa * c;
    u[2] = -cb * s; u[3] = -sb * s;
    u[4] =  cb * s; u[5] = -sb * s;
    u[6] =  ca * c; u[7] =  sa * c;
    float t2 = 0.5f * ld(crx, tid, fcrx);
    gG[720 + tid * 2 + 0] = cosf(t2);              // gCS region [720, 900)
    gG[720 + tid * 2 + 1] = sinf(t2);
  }
}

// -------- fused prep: blocks 0..255 build 2 W columns each (1 wave = 1
// -------- column; gate consts via SGPR scalar loads; zero LDS in circuit);
// -------- blocks 256.. cast x->bf16 grid-stride. ---------------------------
#define CIRC_BLKS 256
#define CAST_BLKS 2048

__global__ __launch_bounds__(128) void prep_kernel(const void* __restrict__ x,
                                                   const float* __restrict__ gG,
                                                   __hip_bfloat16* __restrict__ A,
                                                   __hip_bfloat16* __restrict__ BT) {
  int tid = threadIdx.x;
  if (blockIdx.x < CIRC_BLKS) {
    // runtime self-test of permlane{16,32}_swap element order (wrong order
    // degenerates to identity; shfl path is the correct fallback either way)
    bool plok = false;
#if HAS_PL
    {
      int ln = tid & 63;
      iv2 r32 = __builtin_amdgcn_permlane32_swap(ln, ln, false, false);
      int p32 = (ln & 32) ? r32.x : r32.y;
      iv2 r16 = __builtin_amdgcn_permlane16_swap(ln, ln, false, false);
      int p16 = (ln & 16) ? r16.x : r16.y;
      plok = __all((p32 == (ln ^ 32)) && (p16 == (ln ^ 16))) != 0;
    }
#endif
    int lane = tid & 63, wv = tid >> 6;       // 2 waves
    int k = blockIdx.x * 2 + wv;              // this wave's W column
    float sr[8], si[8];
#pragma unroll
    for (int r = 0; r < 8; ++r) {             // psi = e_k  (idx = lane*8 + r)
      sr[r] = (lane * 8 + r == k) ? 1.f : 0.f;
      si[r] = 0.f;
    }
    if (plok) run_circuit_v<true>(sr, si, gG, gG + 720);
    else      run_circuit_v<false>(sr, si, gG, gG + 720);
#pragma unroll
    for (int r = 0; r < 8; ++r) {
      int j = lane * 8 + r;
      BT[(size_t)j * DIM + k]         = __float2bfloat16(sr[r]);  // Re W[j,k]
      BT[(size_t)(DIM + j) * DIM + k] = __float2bfloat16(si[r]);  // Im W[j,k]
    }
  } else {
    __shared__ int fx;
    if (tid == 0) fx = looks_bf16(x, B_TOT * DIM);
    __syncthreads();
    size_t stride = (size_t)CAST_BLKS * 128 * 8;
    for (size_t i0 = ((size_t)(blockIdx.x - CIRC_BLKS) * 128 + tid) * 8;
         i0 < (size_t)B_TOT * DIM; i0 += stride) {
      if (fx) {
        *(uint4*)(A + i0) = *(const uint4*)((const unsigned short*)x + i0);
      } else {
        const float4* src = (const float4*)((const float*)x + i0);
        float4 a = src[0], b = src[1];
        __hip_bfloat16 o[8];
        o[0] = __float2bfloat16(a.x); o[1] = __float2bfloat16(a.y);
        o[2] = __float2bfloat16(a.z); o[3] = __float2bfloat16(a.w);
        o[4] = __float2bfloat16(b.x); o[5] = __float2bfloat16(b.y);
        o[6] = __float2bfloat16(b.z); o[7] = __float2bfloat16(b.w);
        *(uint4*)(A + i0) = *(uint4*)o;
      }
    }
  }
}

// ------- GEMM 256x256 tile, 8-wave, BK=64, counted-vmcnt pipeline ----------
// Schedule (derived from the verified 256^2 8-phase template invariants):
//   tile t in buf[t&1]; its 4 phases stage tile t+1's half-tiles in order
//   A0,B0,A1,B1; counted s_waitcnt vmcnt(4) + raw s_barrier at phase ends
//   0,1,3 (phase 2 merges into 3). Guarantee chain (vmcnt = oldest-first):
//     end-ph0: <=6 outstanding -> A1(t) landed   (needed by ph1)
//     end-ph1: <=6 outstanding -> B1(t) landed   (needed by ph2/ph3)
//     end-ph3: <=8 outstanding -> A0,B0(t+1) landed (needed by next ph0)
//   Prologue: stage tile0 (8 loads) then vmcnt(4). Epilogue drains 4->2->0.
// LDS 128KiB: [A buf0|A buf1|B buf0|B buf1] each 256x64 bf16, 16B-slot
// XOR swizzle (slot ^= row&7) applied via pre-swizzled global source
// (linear global_load_lds dest) and on the ds_read side (rule #21).
using frag8 = __attribute__((ext_vector_type(8))) short;
using frag4 = __attribute__((ext_vector_type(4))) float;

typedef __attribute__((address_space(1))) const unsigned int GU32;
typedef __attribute__((address_space(3))) unsigned int LU32;
__device__ __forceinline__ void async16(const void* g, void* l) {
  __builtin_amdgcn_global_load_lds((GU32*)g, (LU32*)l, 16, 0, 0);
}

#define VM(N) asm volatile("s_waitcnt vmcnt(" #N ")" ::: "memory")
#define BARR  do { __builtin_amdgcn_sched_barrier(0); \
                   __builtin_amdgcn_s_barrier(); \
                   __builtin_amdgcn_sched_barrier(0); } while (0)

#define STG_A(NB, T1, H) do { \
  async16(gA + ((size_t)((H) * 128) * 512 + (T1) * 64),     dA + (NB) * 16384 + (H) * 8192); \
  async16(gA + ((size_t)((H) * 128 + 8) * 512 + (T1) * 64), dA + (NB) * 16384 + (H) * 8192 + 512); \
} while (0)
#define STG_B(NB, T1, H) do { \
  async16(gB + ((size_t)((H) * 128) * 512 + (T1) * 64),     dB + (NB) * 16384 + (H) * 8192); \
  async16(gB + ((size_t)((H) * 128 + 8) * 512 + (T1) * 64), dB + (NB) * 16384 + (H) * 8192 + 512); \
} while (0)

// One phase: 12 ds_read_b128 (swizzled), stage issue, 16 MFMA under setprio.
#define PHASE(CURB, QM, QN, STG, VMC) do { \
  frag8 paf[4][2], pbf[2][2]; \
  _Pragma("unroll") \
  for (int mi = 0; mi < 4; ++mi) { \
    _Pragma("unroll") \
    for (int kk = 0; kk < 2; ++kk) \
      paf[mi][kk] = *(const frag8*)(lsm + (CURB) * 16384 + \
        ((QM) * 128 + wm * 64 + mi * 16 + r15) * 64 + \
        (((kk * 4 + quad) ^ (r15 & 7)) * 8)); \
  } \
  _Pragma("unroll") \
  for (int ni = 0; ni < 2; ++ni) { \
    _Pragma("unroll") \
    for (int kk = 0; kk < 2; ++kk) \
      pbf[ni][kk] = *(const frag8*)(lsm + 32768 + (CURB) * 16384 + \
        ((QN) * 128 + wn * 32 + ni * 16 + r15) * 64 + \
        (((kk * 4 + quad) ^ (r15 & 7)) * 8)); \
  } \
  STG; \
  __builtin_amdgcn_s_setprio(1); \
  _Pragma("unroll") \
  for (int mi = 0; mi < 4; ++mi) { \
    _Pragma("unroll") \
    for (int ni = 0; ni < 2; ++ni) { \
      acc[QM][mi][QN][ni] = __builtin_amdgcn_mfma_f32_16x16x32_bf16( \
          paf[mi][0], pbf[ni][0], acc[QM][mi][QN][ni], 0, 0, 0); \
      acc[QM][mi][QN][ni] = __builtin_amdgcn_mfma_f32_16x16x32_bf16( \
          paf[mi][1], pbf[ni][1], acc[QM][mi][QN][ni], 0, 0, 0); \
    } \
  } \
  __builtin_amdgcn_s_setprio(0); \
  VMC; \
} while (0)

__global__ __launch_bounds__(512, 2) void gemm_z_kernel(const unsigned short* __restrict__ A,
                                                        const unsigned short* __restrict__ BT,
                                                        float* __restrict__ Zp) {
  __shared__ __align__(16) unsigned short lsm[65536];  // 128 KiB
  int bid = blockIdx.x;
  int xcd = bid & 7;                 // hw round-robins consecutive bids over XCDs
  int ii = bid >> 3;                 // 0..31 per XCD
  int m0 = (xcd * 8 + (ii >> 2)) * 256;   // same-XCD blocks share A panels (L2)
  int n0 = (ii & 3) * 256;
  int tid = threadIdx.x;
  int wv = tid >> 6, lane = tid & 63;
  int wm = wv >> 2, wn = wv & 3;     // 2M x 4N wave grid; per-wave C = 128x64
  int r15 = lane & 15, quad = lane >> 4;
  int lr3 = lane >> 3;
  int scol = ((lane & 7) ^ lr3) * 8; // pre-swizzled source column (elements)
  const unsigned short* gA = A + (size_t)(m0 + wv * 16 + lr3) * 512 + scol;
  const unsigned short* gB = BT + (size_t)(n0 + wv * 16 + lr3) * 512 + scol;
  unsigned short* dA = lsm + wv * 16 * 64;           // wave-uniform LDS dests
  unsigned short* dB = lsm + 32768 + wv * 16 * 64;

  frag4 acc[2][4][2][2] = {};

  // prologue: stage tile 0 (A0,B0,A1,B1), guarantee A0,B0
  STG_A(0, 0, 0); STG_B(0, 0, 0); STG_A(0, 0, 1); STG_B(0, 0, 1);
  VM(4);
  BARR;

#pragma unroll 1
  for (int t = 0; t < 7; ++t) {
    const int cur = t & 1, nb = cur ^ 1;
    PHASE(cur, 0, 0, STG_A(nb, t + 1, 0), VM(4)); BARR;   // consumes A0,B0
    PHASE(cur, 1, 0, STG_B(nb, t + 1, 0), VM(4)); BARR;   // consumes A1,B0
    PHASE(cur, 0, 1, STG_A(nb, t + 1, 1), ;);             // consumes A0,B1
    PHASE(cur, 1, 1, STG_B(nb, t + 1, 1), VM(4)); BARR;   // consumes A1,B1
  }
  // tile 7: no staging; drain 4 -> 2 -> 0
  PHASE(1, 0, 0, ;, VM(2)); BARR;
  PHASE(1, 1, 0, ;, VM(0)); BARR;
  PHASE(1, 0, 1, ;, ;);
  PHASE(1, 1, 1, ;, ;);
  __syncthreads();

  // ---- epilogue: P = acc^2 -> LDS bf16 [256][256], same XOR slot swizzle --
#pragma unroll
  for (int qm = 0; qm < 2; ++qm)
#pragma unroll
    for (int mi = 0; mi < 4; ++mi)
#pragma unroll
      for (int qn = 0; qn < 2; ++qn)
#pragma unroll
        for (int ni = 0; ni < 2; ++ni)
#pragma unroll
          for (int rg = 0; rg < 4; ++rg) {
            float v = acc[qm][mi][qn][ni][rg];
            float p = v * v;
            int prow = qm * 128 + wm * 64 + mi * 16 + quad * 4 + rg;
            int pcol = qn * 128 + wn * 32 + ni * 16 + r15;
            int phys = (pcol >> 3) ^ (prow & 7);
            __hip_bfloat16 h = __float2bfloat16(p);
            lsm[prow * 256 + phys * 8 + (pcol & 7)] = *(unsigned short*)&h;
          }
  __syncthreads();

  // ---- second GEMM: Ztile = P . ST^T, signs computed in-register ----------
  frag8 b2[8];
#pragma unroll
  for (int kk = 0; kk < 8; ++kk) {
    union { frag8 f; unsigned short u[8]; } bb;
#pragma unroll
    for (int e = 0; e < 8; ++e) {
      int j = (n0 + kk * 32 + quad * 8 + e) & 511;
      unsigned short us;
      if (r15 < 9)      us = ((((unsigned)j) >> ((8 - r15) & 31)) & 1) ? 0xBF80 : 0x3F80;
      else if (r15 == 9) us = 0x3F80;
      else               us = 0;
      bb.u[e] = us;
    }
    b2[kk] = bb.f;
  }
  frag4 z2[2] = {};
#pragma unroll
  for (int tt = 0; tt < 2; ++tt) {
    int mt = wv + tt * 8;
#pragma unroll
    for (int kk = 0; kk < 8; ++kk) {
      frag8 a2 = *(const frag8*)(lsm + (mt * 16 + r15) * 256 +
                                 (((kk * 4 + quad) ^ (r15 & 7)) * 8));
      z2[tt] = __builtin_amdgcn_mfma_f32_16x16x32_bf16(a2, b2[kk], z2[tt], 0, 0, 0);
    }
  }
  int panel = n0 >> 8;
  if (r15 < 10) {
#pragma unroll
    for (int tt = 0; tt < 2; ++tt) {
      int mt = wv + tt * 8;
#pragma unroll
      for (int rg = 0; rg < 4; ++rg) {
        int mrow = m0 + mt * 16 + quad * 4 + rg;
        Zp[(size_t)panel * (B_TOT * 10) + (size_t)mrow * 10 + r15] = z2[tt][rg];
      }
    }
  }
}

// ------- final reduction: sum 4 panels, normalize, logits, log_softmax -----
__global__ __launch_bounds__(128) void zred_kernel(const float* __restrict__ Zp,
                                                   const void* __restrict__ fcw,
                                                   const void* __restrict__ fcb,
                                                   float* __restrict__ out) {
  __shared__ int flags[2];
  __shared__ float sW[NCLS * NQ];
  __shared__ float sB[NCLS];
  int tid = threadIdx.x;
  if (tid == 0) {
    flags[0] = looks_bf16(fcw, NCLS * NQ);
    flags[1] = looks_bf16(fcb, NCLS);
  }
  __syncthreads();
  if (tid < NCLS * NQ) sW[tid] = ld(fcw, tid, flags[0]);
  if (tid < NCLS)      sB[tid] = ld(fcb, tid, flags[1]);
  __syncthreads();
  int row = blockIdx.x * 128 + tid;
  float z[10];
#pragma unroll
  for (int q = 0; q < 10; ++q) z[q] = 0.f;
#pragma unroll
  for (int pnl = 0; pnl < 4; ++pnl) {
    const float* p = Zp + (size_t)pnl * (B_TOT * 10) + (size_t)row * 10;
#pragma unroll
    for (int q = 0; q < 10; ++q) z[q] += p[q];
  }
  float invP = 1.0f / z[9];
#pragma unroll
  for (int q = 0; q < NQ; ++q) z[q] *= invP;
  float lg[NCLS], mx = -1e30f;
#pragma unroll
  for (int k = 0; k < NCLS; ++k) {
    float t = sB[k];
#pragma unroll
    for (int q = 0; q < NQ; ++q) t += z[q] * sW[k * NQ + q];
    lg[k] = t; mx = fmaxf(mx, t);
  }
  float se = 0.f;
#pragma unroll
  for (int k = 0; k < NCLS; ++k) se += expf(lg[k] - mx);
  float lse = mx + logf(se);
#pragma unroll
  for (int k = 0; k < NCLS; ++k) out[(size_t)row * NCLS + k] = lg[k] - lse;
}

// ---------------- fallback: round-3 passing monolithic kernel --------------
__global__ __launch_bounds__(256) void qnn_kernel(
    const void* __restrict__ x, const void* __restrict__ rot,
    const void* __restrict__ crx, const void* __restrict__ fcw,
    const void* __restrict__ fcb, float* __restrict__ out) {
  __shared__ __align__(16) float gU[NL * NQ * 8];
  __shared__ __align__(16) float gCS[NL * NQ * 2];
  __shared__ int flags[3];
  int tid = threadIdx.x;
  if (tid == 0) {
    flags[0] = looks_bf16(x, B_TOT * DIM);
    flags[1] = looks_bf16(fcw, NCLS * NQ);
    flags[2] = looks_bf16(fcb, NCLS);
  }
  build_gates(rot, crx, gU, gCS);
  __syncthreads();
  int wid = (blockIdx.x * blockDim.x + tid) >> 6;
  int lane = tid & 63;
  float sr[8], si[8];
  if (flags[0]) {
    const uint4 u = *(const uint4*)((const unsigned short*)x + (size_t)wid * DIM + lane * 8);
    sr[0] = __uint_as_float(u.x << 16); sr[1] = __uint_as_float(u.x & 0xffff0000u);
    sr[2] = __uint_as_float(u.y << 16); sr[3] = __uint_as_float(u.y & 0xffff0000u);
    sr[4] = __uint_as_float(u.z << 16); sr[5] = __uint_as_float(u.z & 0xffff0000u);
    sr[6] = __uint_as_float(u.w << 16); sr[7] = __uint_as_float(u.w & 0xffff0000u);
  } else {
    const float4* xf = (const float4*)((const float*)x + (size_t)wid * DIM) + lane * 2;
    float4 a = xf[0], b = xf[1];
    sr[0] = a.x; sr[1] = a.y; sr[2] = a.z; sr[3] = a.w;
    sr[4] = b.x; sr[5] = b.y; sr[6] = b.z; sr[7] = b.w;
  }
  float nrm = 0.f;
#pragma unroll
  for (int r = 0; r < 8; ++r) { nrm += sr[r] * sr[r]; si[r] = 0.f; }
#pragma unroll
  for (int m = 1; m < 64; m <<= 1) nrm += shx(nrm, m);
  float inv = rsqrtf(nrm);
  inv = inv * (1.5f - 0.5f * nrm * inv * inv);
#pragma unroll
  for (int r = 0; r < 8; ++r) sr[r] *= inv;
  run_circuit(sr, si, gU, gCS);
  float p[8], P = 0.f;
#pragma unroll
  for (int r = 0; r < 8; ++r) { p[r] = sr[r] * sr[r] + si[r] * si[r]; P += p[r]; }
  float z[NQ];
#pragma unroll
  for (int q = 0; q < 6; ++q) z[q] = (lane & (32 >> q)) ? -P : P;
  z[6] = z[7] = z[8] = 0.f;
#pragma unroll
  for (int r = 0; r < 8; ++r) {
    z[6] += (r & 4) ? -p[r] : p[r];
    z[7] += (r & 2) ? -p[r] : p[r];
    z[8] += (r & 1) ? -p[r] : p[r];
  }
#pragma unroll
  for (int m = 1; m < 64; m <<= 1) {
#pragma unroll
    for (int q = 0; q < NQ; ++q) z[q] += shx(z[q], m);
  }
  int ffw = flags[1], ffb = flags[2];
  float lg[NCLS], mx = -1e30f;
#pragma unroll
  for (int k = 0; k < NCLS; ++k) {
    float t = ld(fcb, k, ffb);
#pragma unroll
    for (int q = 0; q < NQ; ++q) t += z[q] * ld(fcw, k * NQ + q, ffw);
    lg[k] = t; mx = fmaxf(mx, t);
  }
  float se = 0.f;
#pragma unroll
  for (int k = 0; k < NCLS; ++k) se += expf(lg[k] - mx);
  float lse = mx + logf(se);
  if (lane < NCLS) out[(size_t)wid * NCLS + lane] = lg[lane] - lse;
}

extern "C" void kernel_launch(void* const* d_in, const int* in_sizes, int n_in,
                              void* d_out, int out_size, void* d_ws, size_t ws_size,
                              hipStream_t stream) {
  const void* x   = d_in[0];
  const void* rot = d_in[1];
  const void* crx = d_in[2];
  const void* fcw = d_in[3];
  const void* fcb = d_in[4];
  float* out = (float*)d_out;
  if (ws_size >= WS_NEED) {
    __hip_bfloat16* A  = (__hip_bfloat16*)((char*)d_ws + A_OFF);
    __hip_bfloat16* BT = (__hip_bfloat16*)((char*)d_ws + BT_OFF);
    float*          Zp = (float*)((char*)d_ws + ZP_OFF);
    float*          gG = (float*)((char*)d_ws + GT_OFF);
    gates_kernel<<<1, 128, 0, stream>>>(rot, crx, gG);
    prep_kernel<<<CIRC_BLKS + CAST_BLKS, 128, 0, stream>>>(x, gG, A, BT);
    gemm_z_kernel<<<(B_TOT / 256) * (1024 / 256), 512, 0, stream>>>(
        (const unsigned short*)A, (const unsigned short*)BT, Zp);
    zred_kernel<<<B_TOT / 128, 128, 0, stream>>>(Zp, fcw, fcb, out);
  } else {
    qnn_kernel<<<(B_TOT * 64) / 256, 256, 0, stream>>>(x, rot, crx, fcw, fcb, out);
  }
}

// Round 8
// 139.677 us; speedup vs baseline: 1.1142x; 1.1142x over previous
//
#include <hip/hip_runtime.h>
#include <hip/hip_bf16.h>
#include <math.h>

#define NQ 9
#define NL 10
#define DIM 512
#define NCLS 10
#define B_TOT 16384

// ws layout (bytes): A bf16 [16384x512] @ 0 (16MB); BT bf16 [1024x512] @ 16MB;
// Zp f32 [4][16384][10] @ 32MB (2.62MB).
// NOTE (R13 lesson): bulk data between workgroups of ONE launch is unsafe on
// CDNA4 (per-XCD L2 non-coherent) — producer->consumer crossings are kernel
// boundaries (prep->gemm, gemm->zred).
#define A_OFF   ((size_t)0)
#define BT_OFF  ((size_t)16 << 20)
#define ZP_OFF  ((size_t)32 << 20)
#define WS_NEED (((size_t)96) << 20)

#if __has_builtin(__builtin_amdgcn_permlane16_swap) && __has_builtin(__builtin_amdgcn_permlane32_swap)
#define HAS_PL 1
#else
#define HAS_PL 0
#endif
typedef int iv2 __attribute__((ext_vector_type(2)));

__device__ __forceinline__ float shx(float v, int m) { return __shfl_xor(v, m, 64); }

// ---- VALU lane-XOR permutes. DPP ctrls: quad_perm<=0xFF, row_ror:8=0x128,
// ---- row_half_mirror=0x141. XOR4 = quad[3,2,1,0](i^3) o half_mirror(i^7).
template<int CTRL>
__device__ __forceinline__ float dppq(float v) {
  return __int_as_float(__builtin_amdgcn_update_dpp(
      0, __float_as_int(v), CTRL, 0xF, 0xF, true));
}

// permlane{16,32}_swap with both inputs = v: one output half-broadcasts lo,
// the other hi; partner(lane^M) = select on the lane bit. A wrong
// element-order assumption degenerates to identity -> runtime self-test.
template<int M, bool PL>
__device__ __forceinline__ float shxt(float v) {
  if constexpr (M == 1)       return dppq<0xB1>(v);
  else if constexpr (M == 2)  return dppq<0x4E>(v);
  else if constexpr (M == 4)  return dppq<0x1B>(dppq<0x141>(v));
  else if constexpr (M == 8)  return dppq<0x128>(v);
  else if constexpr (M == 16) {
#if HAS_PL
    if constexpr (PL) {
      iv2 r = __builtin_amdgcn_permlane16_swap(__float_as_int(v), __float_as_int(v),
                                               false, false);
      return __int_as_float((threadIdx.x & 16) ? r.x : r.y);
    }
#endif
    return shx(v, 16);
  } else {
#if HAS_PL
    if constexpr (PL) {
      iv2 r = __builtin_amdgcn_permlane32_swap(__float_as_int(v), __float_as_int(v),
                                               false, false);
      return __int_as_float((threadIdx.x & 32) ? r.x : r.y);
    }
#endif
    return shx(v, 32);
  }
}

__device__ __forceinline__ int looks_bf16(const void* p, int count) {
  const unsigned short* u = (const unsigned short*)p;
  int n = count < 64 ? count : 64;
  int good = 0;
  for (int i = 0; i < n; ++i) {
    unsigned short v = u[i];
    int e = (v >> 7) & 0xFF;
    good += (e >= 100 && e <= 140) || ((v & 0x7FFF) == 0);
  }
  return good * 8 >= n * 7;
}

__device__ __forceinline__ float ld(const void* p, int i, int isbf) {
  if (isbf) return __uint_as_float(((unsigned)((const unsigned short*)p)[i]) << 16);
  return ((const float*)p)[i];
}

// ---------------- 8-amp gate helpers (verified R3; used by fallback) -------
template<int M>
__device__ __forceinline__ void rot_x(float (&sr)[8], float (&si)[8], const float* u) {
  float4 uA = *(const float4*)u;
  float4 uB = *(const float4*)(u + 4);
  bool hi = (threadIdx.x & M) != 0;
  float ar = hi ? uB.z : uA.x, ai = hi ? uB.w : uA.y;
  float br = hi ? uB.x : uA.z, bi = hi ? uB.y : uA.w;
#pragma unroll
  for (int r = 0; r < 8; ++r) {
    float pr = shx(sr[r], M), pi = shx(si[r], M);
    float nr = ar * sr[r] - ai * si[r] + br * pr - bi * pi;
    float ni = ar * si[r] + ai * sr[r] + br * pi + bi * pr;
    sr[r] = nr; si[r] = ni;
  }
}
template<int S>
__device__ __forceinline__ void rot_r(float (&sr)[8], float (&si)[8], const float* u) {
  float4 uA = *(const float4*)u;
  float4 uB = *(const float4*)(u + 4);
#pragma unroll
  for (int r0 = 0; r0 < 8; ++r0) {
    if (r0 & S) continue;
    int r1 = r0 + S;
    float a0r = sr[r0], a0i = si[r0], a1r = sr[r1], a1i = si[r1];
    sr[r0] = uA.x * a0r - uA.y * a0i + uA.z * a1r - uA.w * a1i;
    si[r0] = uA.x * a0i + uA.y * a0r + uA.z * a1i + uA.w * a1r;
    sr[r1] = uB.x * a0r - uB.y * a0i + uB.z * a1r - uB.w * a1i;
    si[r1] = uB.x * a0i + uB.y * a0r + uB.z * a1i + uB.w * a1r;
  }
}
template<int MC, int MT>
__device__ __forceinline__ void crx_ll(float (&sr)[8], float (&si)[8], const float* cs) {
  bool ctrl = (threadIdx.x & MC) != 0;
  float c = ctrl ? cs[0] : 1.0f;
  float s = ctrl ? cs[1] : 0.0f;
#pragma unroll
  for (int r = 0; r < 8; ++r) {
    float pr = shx(sr[r], MT), pi = shx(si[r], MT);
    float nr = c * sr[r] + s * pi;
    float ni = c * si[r] - s * pr;
    sr[r] = nr; si[r] = ni;
  }
}
template<int MC, int ST>
__device__ __forceinline__ void crx_lr(float (&sr)[8], float (&si)[8], const float* cs) {
  bool ctrl = (threadIdx.x & MC) != 0;
  float c = ctrl ? cs[0] : 1.0f;
  float s = ctrl ? cs[1] : 0.0f;
#pragma unroll
  for (int r0 = 0; r0 < 8; ++r0) {
    if (r0 & ST) continue;
    int r1 = r0 + ST;
    float a0r = sr[r0], a0i = si[r0], a1r = sr[r1], a1i = si[r1];
    sr[r0] = c * a0r + s * a1i;  si[r0] = c * a0i - s * a1r;
    sr[r1] = c * a1r + s * a0i;  si[r1] = c * a1i - s * a0r;
  }
}
template<int PC, int ST>
__device__ __forceinline__ void crx_rr(float (&sr)[8], float (&si)[8], const float* cs) {
  float c = cs[0], s = cs[1];
#pragma unroll
  for (int r0 = 0; r0 < 8; ++r0) {
    if (r0 & ST) continue;
    if (!((r0 >> PC) & 1)) continue;
    int r1 = r0 + ST;
    float a0r = sr[r0], a0i = si[r0], a1r = sr[r1], a1i = si[r1];
    sr[r0] = c * a0r + s * a1i;  si[r0] = c * a0i - s * a1r;
    sr[r1] = c * a1r + s * a0i;  si[r1] = c * a1i - s * a0r;
  }
}
template<int PC, int MT>
__device__ __forceinline__ void crx_rl(float (&sr)[8], float (&si)[8], const float* cs) {
  float c = cs[0], s = cs[1];
#pragma unroll
  for (int r = 0; r < 8; ++r) {
    if (!((r >> PC) & 1)) continue;
    float pr = shx(sr[r], MT), pi = shx(si[r], MT);
    float nr = c * sr[r] + s * pi;
    float ni = c * si[r] - s * pr;
    sr[r] = nr; si[r] = ni;
  }
}

// -------- VALUE-taking gate variants (R6 post-mortem: per-gate constant
// -------- fetch was the serial ~560cyc/gate cost in EVERY prior variant —
// -------- constants now preloaded per-LAYER into named registers; gates are
// -------- pure register+VALU, shuffles batched DPP/permlane). --------------
template<int M, bool PL>
__device__ __forceinline__ void rot_xv(float (&sr)[8], float (&si)[8],
                                       float4 uA, float4 uB) {
  bool hi = (threadIdx.x & M) != 0;
  float ar = hi ? uB.z : uA.x, ai = hi ? uB.w : uA.y;
  float br = hi ? uB.x : uA.z, bi = hi ? uB.y : uA.w;
  float pr[8], pi[8];
#pragma unroll
  for (int r = 0; r < 8; ++r) { pr[r] = shxt<M, PL>(sr[r]); pi[r] = shxt<M, PL>(si[r]); }
#pragma unroll
  for (int r = 0; r < 8; ++r) {
    float nr = ar * sr[r] - ai * si[r] + br * pr[r] - bi * pi[r];
    float ni = ar * si[r] + ai * sr[r] + br * pi[r] + bi * pr[r];
    sr[r] = nr; si[r] = ni;
  }
}
template<int S>
__device__ __forceinline__ void rot_rv(float (&sr)[8], float (&si)[8],
                                       float4 uA, float4 uB) {
#pragma unroll
  for (int r0 = 0; r0 < 8; ++r0) {
    if (r0 & S) continue;
    int r1 = r0 + S;
    float a0r = sr[r0], a0i = si[r0], a1r = sr[r1], a1i = si[r1];
    sr[r0] = uA.x * a0r - uA.y * a0i + uA.z * a1r - uA.w * a1i;
    si[r0] = uA.x * a0i + uA.y * a0r + uA.z * a1i + uA.w * a1r;
    sr[r1] = uB.x * a0r - uB.y * a0i + uB.z * a1r - uB.w * a1i;
    si[r1] = uB.x * a0i + uB.y * a0r + uB.z * a1i + uB.w * a1r;
  }
}
template<int MC, int MT, bool PL>
__device__ __forceinline__ void crx_llv(float (&sr)[8], float (&si)[8],
                                        float cc, float ss) {
  bool ctrl = (threadIdx.x & MC) != 0;
  float c = ctrl ? cc : 1.0f;
  float s = ctrl ? ss : 0.0f;
  float pr[8], pi[8];
#pragma unroll
  for (int r = 0; r < 8; ++r) { pr[r] = shxt<MT, PL>(sr[r]); pi[r] = shxt<MT, PL>(si[r]); }
#pragma unroll
  for (int r = 0; r < 8; ++r) {
    float nr = c * sr[r] + s * pi[r];
    float ni = c * si[r] - s * pr[r];
    sr[r] = nr; si[r] = ni;
  }
}
template<int MC, int ST>
__device__ __forceinline__ void crx_lrv(float (&sr)[8], float (&si)[8],
                                        float cc, float ss) {
  bool ctrl = (threadIdx.x & MC) != 0;
  float c = ctrl ? cc : 1.0f;
  float s = ctrl ? ss : 0.0f;
#pragma unroll
  for (int r0 = 0; r0 < 8; ++r0) {
    if (r0 & ST) continue;
    int r1 = r0 + ST;
    float a0r = sr[r0], a0i = si[r0], a1r = sr[r1], a1i = si[r1];
    sr[r0] = c * a0r + s * a1i;  si[r0] = c * a0i - s * a1r;
    sr[r1] = c * a1r + s * a0i;  si[r1] = c * a1i - s * a0r;
  }
}
template<int PC, int ST>
__device__ __forceinline__ void crx_rrv(float (&sr)[8], float (&si)[8],
                                        float c, float s) {
#pragma unroll
  for (int r0 = 0; r0 < 8; ++r0) {
    if (r0 & ST) continue;
    if (!((r0 >> PC) & 1)) continue;
    int r1 = r0 + ST;
    float a0r = sr[r0], a0i = si[r0], a1r = sr[r1], a1i = si[r1];
    sr[r0] = c * a0r + s * a1i;  si[r0] = c * a0i - s * a1r;
    sr[r1] = c * a1r + s * a0i;  si[r1] = c * a1i - s * a0r;
  }
}
template<bool PL>
__device__ __forceinline__ void crx_rlv032(float (&sr)[8], float (&si)[8],
                                           float c, float s) {
  float pr[4], pi[4];
#pragma unroll
  for (int t = 0; t < 4; ++t) {
    int r = 2 * t + 1;
    pr[t] = shxt<32, PL>(sr[r]); pi[t] = shxt<32, PL>(si[r]);
  }
#pragma unroll
  for (int t = 0; t < 4; ++t) {
    int r = 2 * t + 1;
    float nr = c * sr[r] + s * pi[t];
    float ni = c * si[r] - s * pr[t];
    sr[r] = nr; si[r] = ni;
  }
}

__device__ __forceinline__ void build_gates(const void* rot, const void* crx,
                                            float* gU, float* gCS) {
  int tid = threadIdx.x;
  __shared__ int gflags[2];
  if (tid == 0) {
    gflags[0] = looks_bf16(rot, NL * NQ * 3);
    gflags[1] = looks_bf16(crx, NL * NQ);
  }
  __syncthreads();
  if (tid < NL * NQ) {
    int frot = gflags[0], fcrx = gflags[1];
    float phi = ld(rot, tid * 3 + 0, frot);
    float th  = ld(rot, tid * 3 + 1, frot);
    float om  = ld(rot, tid * 3 + 2, frot);
    float c = cosf(0.5f * th), s = sinf(0.5f * th);
    float a = 0.5f * (phi + om), b = 0.5f * (phi - om);
    float ca = cosf(a), sa = sinf(a), cb = cosf(b), sb = sinf(b);
    float* u = gU + tid * 8;
    u[0] =  ca * c; u[1] = -sa * c;
    u[2] = -cb * s; u[3] = -sb * s;
    u[4] =  cb * s; u[5] = -sb * s;
    u[6] =  ca * c; u[7] =  sa * c;
    float t2 = 0.5f * ld(crx, tid, fcrx);
    gCS[tid * 2 + 0] = cosf(t2);
    gCS[tid * 2 + 1] = sinf(t2);
  }
  __syncthreads();
}

__device__ __forceinline__ void run_circuit(float (&sr)[8], float (&si)[8],
                                            const float* gU, const float* gCS) {
#pragma unroll 1
  for (int n = 0; n < NL; ++n) {
    const float* U  = gU  + n * NQ * 8;
    const float* CS = gCS + n * NQ * 2;
    rot_x<32>(sr, si, U + 0 * 8);
    rot_x<16>(sr, si, U + 1 * 8);
    rot_x< 8>(sr, si, U + 2 * 8);
    rot_x< 4>(sr, si, U + 3 * 8);
    rot_x< 2>(sr, si, U + 4 * 8);
    rot_x< 1>(sr, si, U + 5 * 8);
    rot_r< 4>(sr, si, U + 6 * 8);
    rot_r< 2>(sr, si, U + 7 * 8);
    rot_r< 1>(sr, si, U + 8 * 8);
    crx_ll<32, 16>(sr, si, CS + 0 * 2);
    crx_ll<16,  8>(sr, si, CS + 1 * 2);
    crx_ll< 8,  4>(sr, si, CS + 2 * 2);
    crx_ll< 4,  2>(sr, si, CS + 3 * 2);
    crx_ll< 2,  1>(sr, si, CS + 4 * 2);
    crx_lr< 1,  4>(sr, si, CS + 5 * 2);
    crx_rr< 2,  2>(sr, si, CS + 6 * 2);
    crx_rr< 1,  1>(sr, si, CS + 7 * 2);
    crx_rl< 0, 32>(sr, si, CS + 8 * 2);
  }
}

// Per-LAYER register-preloaded circuit: 23 ds_read_b128 (wave-uniform =>
// broadcast, conflict-free) issued together, sched_barrier pins them before
// the 18 register-only gates -> ONE lgkmcnt wait per layer, not per gate.
template<bool PL>
__device__ __forceinline__ void run_circuit_L(float (&sr)[8], float (&si)[8],
                                              const float* gU, const float* gC20) {
#pragma unroll 1
  for (int n = 0; n < NL; ++n) {
    const float4* Up = (const float4*)(gU + n * 72);
    const float4* Cp = (const float4*)(gC20 + n * 20);
    float4 u0 = Up[0],  u1 = Up[1],  u2 = Up[2],  u3 = Up[3],  u4 = Up[4];
    float4 u5 = Up[5],  u6 = Up[6],  u7 = Up[7],  u8 = Up[8],  u9 = Up[9];
    float4 u10 = Up[10], u11 = Up[11], u12 = Up[12], u13 = Up[13], u14 = Up[14];
    float4 u15 = Up[15], u16 = Up[16], u17 = Up[17];
    float4 c0 = Cp[0], c1 = Cp[1], c2 = Cp[2], c3 = Cp[3], c4 = Cp[4];
    __builtin_amdgcn_sched_barrier(0);
    rot_xv<32, PL>(sr, si, u0,  u1);
    rot_xv<16, PL>(sr, si, u2,  u3);
    rot_xv< 8, PL>(sr, si, u4,  u5);
    rot_xv< 4, PL>(sr, si, u6,  u7);
    rot_xv< 2, PL>(sr, si, u8,  u9);
    rot_xv< 1, PL>(sr, si, u10, u11);
    rot_rv< 4>(sr, si, u12, u13);
    rot_rv< 2>(sr, si, u14, u15);
    rot_rv< 1>(sr, si, u16, u17);
    crx_llv<32, 16, PL>(sr, si, c0.x, c0.y);
    crx_llv<16,  8, PL>(sr, si, c0.z, c0.w);
    crx_llv< 8,  4, PL>(sr, si, c1.x, c1.y);
    crx_llv< 4,  2, PL>(sr, si, c1.z, c1.w);
    crx_llv< 2,  1, PL>(sr, si, c2.x, c2.y);
    crx_lrv< 1,  4>(sr, si, c2.z, c2.w);
    crx_rrv< 2,  2>(sr, si, c3.x, c3.y);
    crx_rrv< 1,  1>(sr, si, c3.z, c3.w);
    crx_rlv032<PL>(sr, si, c4.x, c4.y);
  }
}

// -------- fused prep: blocks 0..255 build 2 W columns each (1 wave = 1
// -------- column; per-layer register-preloaded constants; batched VALU
// -------- permute shuffles); blocks 256.. cast x->bf16 grid-stride. --------
#define CIRC_BLKS 256
#define CAST_BLKS 2048

__global__ __launch_bounds__(128) void prep_kernel(const void* __restrict__ x,
                                                   const void* __restrict__ rot,
                                                   const void* __restrict__ crx,
                                                   __hip_bfloat16* __restrict__ A,
                                                   __hip_bfloat16* __restrict__ BT) {
  int tid = threadIdx.x;
  if (blockIdx.x < CIRC_BLKS) {
    __shared__ __align__(16) float gU[NL * 72];
    __shared__ __align__(16) float gC[NL * 20];   // CS padded to 20/layer
    {
      __shared__ int gflags[2];
      if (tid == 0) {
        gflags[0] = looks_bf16(rot, NL * NQ * 3);
        gflags[1] = looks_bf16(crx, NL * NQ);
      }
      __syncthreads();
      if (tid < NL * NQ) {
        int frot = gflags[0], fcrx = gflags[1];
        float phi = ld(rot, tid * 3 + 0, frot);
        float th  = ld(rot, tid * 3 + 1, frot);
        float om  = ld(rot, tid * 3 + 2, frot);
        float c = cosf(0.5f * th), s = sinf(0.5f * th);
        float a = 0.5f * (phi + om), b = 0.5f * (phi - om);
        float ca = cosf(a), sa = sinf(a), cb = cosf(b), sb = sinf(b);
        float* u = gU + tid * 8;
        u[0] =  ca * c; u[1] = -sa * c;
        u[2] = -cb * s; u[3] = -sb * s;
        u[4] =  cb * s; u[5] = -sb * s;
        u[6] =  ca * c; u[7] =  sa * c;
        int n = tid / 9, q = tid - n * 9;
        float t2 = 0.5f * ld(crx, tid, fcrx);
        gC[n * 20 + q * 2 + 0] = cosf(t2);
        gC[n * 20 + q * 2 + 1] = sinf(t2);
      }
      if (tid < NL * 2) gC[(tid >> 1) * 20 + 18 + (tid & 1)] = 0.f;  // pad
      __syncthreads();
    }
    // runtime self-test of permlane{16,32}_swap element order (wrong order
    // degenerates to identity; shfl path is the correct fallback either way)
    bool plok = false;
#if HAS_PL
    {
      int ln = tid & 63;
      iv2 r32 = __builtin_amdgcn_permlane32_swap(ln, ln, false, false);
      int p32 = (ln & 32) ? r32.x : r32.y;
      iv2 r16 = __builtin_amdgcn_permlane16_swap(ln, ln, false, false);
      int p16 = (ln & 16) ? r16.x : r16.y;
      plok = __all((p32 == (ln ^ 32)) && (p16 == (ln ^ 16))) != 0;
    }
#endif
    int lane = tid & 63, wv = tid >> 6;       // 2 waves
    int k = blockIdx.x * 2 + wv;              // this wave's W column
    float sr[8], si[8];
#pragma unroll
    for (int r = 0; r < 8; ++r) {             // psi = e_k  (idx = lane*8 + r)
      sr[r] = (lane * 8 + r == k) ? 1.f : 0.f;
      si[r] = 0.f;
    }
    if (plok) run_circuit_L<true>(sr, si, gU, gC);
    else      run_circuit_L<false>(sr, si, gU, gC);
#pragma unroll
    for (int r = 0; r < 8; ++r) {
      int j = lane * 8 + r;
      BT[(size_t)j * DIM + k]         = __float2bfloat16(sr[r]);  // Re W[j,k]
      BT[(size_t)(DIM + j) * DIM + k] = __float2bfloat16(si[r]);  // Im W[j,k]
    }
  } else {
    __shared__ int fx;
    if (tid == 0) fx = looks_bf16(x, B_TOT * DIM);
    __syncthreads();
    size_t stride = (size_t)CAST_BLKS * 128 * 8;
    for (size_t i0 = ((size_t)(blockIdx.x - CIRC_BLKS) * 128 + tid) * 8;
         i0 < (size_t)B_TOT * DIM; i0 += stride) {
      if (fx) {
        *(uint4*)(A + i0) = *(const uint4*)((const unsigned short*)x + i0);
      } else {
        const float4* src = (const float4*)((const float*)x + i0);
        float4 a = src[0], b = src[1];
        __hip_bfloat16 o[8];
        o[0] = __float2bfloat16(a.x); o[1] = __float2bfloat16(a.y);
        o[2] = __float2bfloat16(a.z); o[3] = __float2bfloat16(a.w);
        o[4] = __float2bfloat16(b.x); o[5] = __float2bfloat16(b.y);
        o[6] = __float2bfloat16(b.z); o[7] = __float2bfloat16(b.w);
        *(uint4*)(A + i0) = *(uint4*)o;
      }
    }
  }
}

// ------- GEMM 256x256 tile, 8-wave, BK=64, counted-vmcnt pipeline ----------
// Schedule (derived from the verified 256^2 8-phase template invariants):
//   tile t in buf[t&1]; its 4 phases stage tile t+1's half-tiles in order
//   A0,B0,A1,B1; counted s_waitcnt vmcnt(4) + raw s_barrier at phase ends
//   0,1,3 (phase 2 merges into 3). Guarantee chain (vmcnt = oldest-first):
//     end-ph0: <=6 outstanding -> A1(t) landed   (needed by ph1)
//     end-ph1: <=6 outstanding -> B1(t) landed   (needed by ph2/ph3)
//     end-ph3: <=8 outstanding -> A0,B0(t+1) landed (needed by next ph0)
//   Prologue: stage tile0 (8 loads) then vmcnt(4). Epilogue drains 4->2->0.
// LDS 128KiB: [A buf0|A buf1|B buf0|B buf1] each 256x64 bf16, 16B-slot
// XOR swizzle (slot ^= row&7) applied via pre-swizzled global source
// (linear global_load_lds dest) and on the ds_read side (rule #21).
using frag8 = __attribute__((ext_vector_type(8))) short;
using frag4 = __attribute__((ext_vector_type(4))) float;

typedef __attribute__((address_space(1))) const unsigned int GU32;
typedef __attribute__((address_space(3))) unsigned int LU32;
__device__ __forceinline__ void async16(const void* g, void* l) {
  __builtin_amdgcn_global_load_lds((GU32*)g, (LU32*)l, 16, 0, 0);
}

#define VM(N) asm volatile("s_waitcnt vmcnt(" #N ")" ::: "memory")
#define BARR  do { __builtin_amdgcn_sched_barrier(0); \
                   __builtin_amdgcn_s_barrier(); \
                   __builtin_amdgcn_sched_barrier(0); } while (0)

#define STG_A(NB, T1, H) do { \
  async16(gA + ((size_t)((H) * 128) * 512 + (T1) * 64),     dA + (NB) * 16384 + (H) * 8192); \
  async16(gA + ((size_t)((H) * 128 + 8) * 512 + (T1) * 64), dA + (NB) * 16384 + (H) * 8192 + 512); \
} while (0)
#define STG_B(NB, T1, H) do { \
  async16(gB + ((size_t)((H) * 128) * 512 + (T1) * 64),     dB + (NB) * 16384 + (H) * 8192); \
  async16(gB + ((size_t)((H) * 128 + 8) * 512 + (T1) * 64), dB + (NB) * 16384 + (H) * 8192 + 512); \
} while (0)

// One phase: 12 ds_read_b128 (swizzled), stage issue, 16 MFMA under setprio.
#define PHASE(CURB, QM, QN, STG, VMC) do { \
  frag8 paf[4][2], pbf[2][2]; \
  _Pragma("unroll") \
  for (int mi = 0; mi < 4; ++mi) { \
    _Pragma("unroll") \
    for (int kk = 0; kk < 2; ++kk) \
      paf[mi][kk] = *(const frag8*)(lsm + (CURB) * 16384 + \
        ((QM) * 128 + wm * 64 + mi * 16 + r15) * 64 + \
        (((kk * 4 + quad) ^ (r15 & 7)) * 8)); \
  } \
  _Pragma("unroll") \
  for (int ni = 0; ni < 2; ++ni) { \
    _Pragma("unroll") \
    for (int kk = 0; kk < 2; ++kk) \
      pbf[ni][kk] = *(const frag8*)(lsm + 32768 + (CURB) * 16384 + \
        ((QN) * 128 + wn * 32 + ni * 16 + r15) * 64 + \
        (((kk * 4 + quad) ^ (r15 & 7)) * 8)); \
  } \
  STG; \
  __builtin_amdgcn_s_setprio(1); \
  _Pragma("unroll") \
  for (int mi = 0; mi < 4; ++mi) { \
    _Pragma("unroll") \
    for (int ni = 0; ni < 2; ++ni) { \
      acc[QM][mi][QN][ni] = __builtin_amdgcn_mfma_f32_16x16x32_bf16( \
          paf[mi][0], pbf[ni][0], acc[QM][mi][QN][ni], 0, 0, 0); \
      acc[QM][mi][QN][ni] = __builtin_amdgcn_mfma_f32_16x16x32_bf16( \
          paf[mi][1], pbf[ni][1], acc[QM][mi][QN][ni], 0, 0, 0); \
    } \
  } \
  __builtin_amdgcn_s_setprio(0); \
  VMC; \
} while (0)

__global__ __launch_bounds__(512, 2) void gemm_z_kernel(const unsigned short* __restrict__ A,
                                                        const unsigned short* __restrict__ BT,
                                                        float* __restrict__ Zp) {
  __shared__ __align__(16) unsigned short lsm[65536];  // 128 KiB
  int bid = blockIdx.x;
  int xcd = bid & 7;                 // hw round-robins consecutive bids over XCDs
  int ii = bid >> 3;                 // 0..31 per XCD
  int m0 = (xcd * 8 + (ii >> 2)) * 256;   // same-XCD blocks share A panels (L2)
  int n0 = (ii & 3) * 256;
  int tid = threadIdx.x;
  int wv = tid >> 6, lane = tid & 63;
  int wm = wv >> 2, wn = wv & 3;     // 2M x 4N wave grid; per-wave C = 128x64
  int r15 = lane & 15, quad = lane >> 4;
  int lr3 = lane >> 3;
  int scol = ((lane & 7) ^ lr3) * 8; // pre-swizzled source column (elements)
  const unsigned short* gA = A + (size_t)(m0 + wv * 16 + lr3) * 512 + scol;
  const unsigned short* gB = BT + (size_t)(n0 + wv * 16 + lr3) * 512 + scol;
  unsigned short* dA = lsm + wv * 16 * 64;           // wave-uniform LDS dests
  unsigned short* dB = lsm + 32768 + wv * 16 * 64;

  frag4 acc[2][4][2][2] = {};

  // prologue: stage tile 0 (A0,B0,A1,B1), guarantee A0,B0
  STG_A(0, 0, 0); STG_B(0, 0, 0); STG_A(0, 0, 1); STG_B(0, 0, 1);
  VM(4);
  BARR;

#pragma unroll 1
  for (int t = 0; t < 7; ++t) {
    const int cur = t & 1, nb = cur ^ 1;
    PHASE(cur, 0, 0, STG_A(nb, t + 1, 0), VM(4)); BARR;   // consumes A0,B0
    PHASE(cur, 1, 0, STG_B(nb, t + 1, 0), VM(4)); BARR;   // consumes A1,B0
    PHASE(cur, 0, 1, STG_A(nb, t + 1, 1), ;);             // consumes A0,B1
    PHASE(cur, 1, 1, STG_B(nb, t + 1, 1), VM(4)); BARR;   // consumes A1,B1
  }
  // tile 7: no staging; drain 4 -> 2 -> 0
  PHASE(1, 0, 0, ;, VM(2)); BARR;
  PHASE(1, 1, 0, ;, VM(0)); BARR;
  PHASE(1, 0, 1, ;, ;);
  PHASE(1, 1, 1, ;, ;);
  __syncthreads();

  // ---- epilogue: P = acc^2 -> LDS bf16 [256][256], same XOR slot swizzle --
#pragma unroll
  for (int qm = 0; qm < 2; ++qm)
#pragma unroll
    for (int mi = 0; mi < 4; ++mi)
#pragma unroll
      for (int qn = 0; qn < 2; ++qn)
#pragma unroll
        for (int ni = 0; ni < 2; ++ni)
#pragma unroll
          for (int rg = 0; rg < 4; ++rg) {
            float v = acc[qm][mi][qn][ni][rg];
            float p = v * v;
            int prow = qm * 128 + wm * 64 + mi * 16 + quad * 4 + rg;
            int pcol = qn * 128 + wn * 32 + ni * 16 + r15;
            int phys = (pcol >> 3) ^ (prow & 7);
            __hip_bfloat16 h = __float2bfloat16(p);
            lsm[prow * 256 + phys * 8 + (pcol & 7)] = *(unsigned short*)&h;
          }
  __syncthreads();

  // ---- second GEMM: Ztile = P . ST^T, signs computed in-register ----------
  frag8 b2[8];
#pragma unroll
  for (int kk = 0; kk < 8; ++kk) {
    union { frag8 f; unsigned short u[8]; } bb;
#pragma unroll
    for (int e = 0; e < 8; ++e) {
      int j = (n0 + kk * 32 + quad * 8 + e) & 511;
      unsigned short us;
      if (r15 < 9)      us = ((((unsigned)j) >> ((8 - r15) & 31)) & 1) ? 0xBF80 : 0x3F80;
      else if (r15 == 9) us = 0x3F80;
      else               us = 0;
      bb.u[e] = us;
    }
    b2[kk] = bb.f;
  }
  frag4 z2[2] = {};
#pragma unroll
  for (int tt = 0; tt < 2; ++tt) {
    int mt = wv + tt * 8;
#pragma unroll
    for (int kk = 0; kk < 8; ++kk) {
      frag8 a2 = *(const frag8*)(lsm + (mt * 16 + r15) * 256 +
                                 (((kk * 4 + quad) ^ (r15 & 7)) * 8));
      z2[tt] = __builtin_amdgcn_mfma_f32_16x16x32_bf16(a2, b2[kk], z2[tt], 0, 0, 0);
    }
  }
  int panel = n0 >> 8;
  if (r15 < 10) {
#pragma unroll
    for (int tt = 0; tt < 2; ++tt) {
      int mt = wv + tt * 8;
#pragma unroll
      for (int rg = 0; rg < 4; ++rg) {
        int mrow = m0 + mt * 16 + quad * 4 + rg;
        Zp[(size_t)panel * (B_TOT * 10) + (size_t)mrow * 10 + r15] = z2[tt][rg];
      }
    }
  }
}

// ------- final reduction: sum 4 panels, normalize, logits, log_softmax -----
__global__ __launch_bounds__(128) void zred_kernel(const float* __restrict__ Zp,
                                                   const void* __restrict__ fcw,
                                                   const void* __restrict__ fcb,
                                                   float* __restrict__ out) {
  __shared__ int flags[2];
  __shared__ float sW[NCLS * NQ];
  __shared__ float sB[NCLS];
  int tid = threadIdx.x;
  if (tid == 0) {
    flags[0] = looks_bf16(fcw, NCLS * NQ);
    flags[1] = looks_bf16(fcb, NCLS);
  }
  __syncthreads();
  if (tid < NCLS * NQ) sW[tid] = ld(fcw, tid, flags[0]);
  if (tid < NCLS)      sB[tid] = ld(fcb, tid, flags[1]);
  __syncthreads();
  int row = blockIdx.x * 128 + tid;
  float z[10];
#pragma unroll
  for (int q = 0; q < 10; ++q) z[q] = 0.f;
#pragma unroll
  for (int pnl = 0; pnl < 4; ++pnl) {
    const float* p = Zp + (size_t)pnl * (B_TOT * 10) + (size_t)row * 10;
#pragma unroll
    for (int q = 0; q < 10; ++q) z[q] += p[q];
  }
  float invP = 1.0f / z[9];
#pragma unroll
  for (int q = 0; q < NQ; ++q) z[q] *= invP;
  float lg[NCLS], mx = -1e30f;
#pragma unroll
  for (int k = 0; k < NCLS; ++k) {
    float t = sB[k];
#pragma unroll
    for (int q = 0; q < NQ; ++q) t += z[q] * sW[k * NQ + q];
    lg[k] = t; mx = fmaxf(mx, t);
  }
  float se = 0.f;
#pragma unroll
  for (int k = 0; k < NCLS; ++k) se += expf(lg[k] - mx);
  float lse = mx + logf(se);
#pragma unroll
  for (int k = 0; k < NCLS; ++k) out[(size_t)row * NCLS + k] = lg[k] - lse;
}

// ---------------- fallback: round-3 passing monolithic kernel --------------
__global__ __launch_bounds__(256) void qnn_kernel(
    const void* __restrict__ x, const void* __restrict__ rot,
    const void* __restrict__ crx, const void* __restrict__ fcw,
    const void* __restrict__ fcb, float* __restrict__ out) {
  __shared__ __align__(16) float gU[NL * NQ * 8];
  __shared__ __align__(16) float gCS[NL * NQ * 2];
  __shared__ int flags[3];
  int tid = threadIdx.x;
  if (tid == 0) {
    flags[0] = looks_bf16(x, B_TOT * DIM);
    flags[1] = looks_bf16(fcw, NCLS * NQ);
    flags[2] = looks_bf16(fcb, NCLS);
  }
  build_gates(rot, crx, gU, gCS);
  __syncthreads();
  int wid = (blockIdx.x * blockDim.x + tid) >> 6;
  int lane = tid & 63;
  float sr[8], si[8];
  if (flags[0]) {
    const uint4 u = *(const uint4*)((const unsigned short*)x + (size_t)wid * DIM + lane * 8);
    sr[0] = __uint_as_float(u.x << 16); sr[1] = __uint_as_float(u.x & 0xffff0000u);
    sr[2] = __uint_as_float(u.y << 16); sr[3] = __uint_as_float(u.y & 0xffff0000u);
    sr[4] = __uint_as_float(u.z << 16); sr[5] = __uint_as_float(u.z & 0xffff0000u);
    sr[6] = __uint_as_float(u.w << 16); sr[7] = __uint_as_float(u.w & 0xffff0000u);
  } else {
    const float4* xf = (const float4*)((const float*)x + (size_t)wid * DIM) + lane * 2;
    float4 a = xf[0], b = xf[1];
    sr[0] = a.x; sr[1] = a.y; sr[2] = a.z; sr[3] = a.w;
    sr[4] = b.x; sr[5] = b.y; sr[6] = b.z; sr[7] = b.w;
  }
  float nrm = 0.f;
#pragma unroll
  for (int r = 0; r < 8; ++r) { nrm += sr[r] * sr[r]; si[r] = 0.f; }
#pragma unroll
  for (int m = 1; m < 64; m <<= 1) nrm += shx(nrm, m);
  float inv = rsqrtf(nrm);
  inv = inv * (1.5f - 0.5f * nrm * inv * inv);
#pragma unroll
  for (int r = 0; r < 8; ++r) sr[r] *= inv;
  run_circuit(sr, si, gU, gCS);
  float p[8], P = 0.f;
#pragma unroll
  for (int r = 0; r < 8; ++r) { p[r] = sr[r] * sr[r] + si[r] * si[r]; P += p[r]; }
  float z[NQ];
#pragma unroll
  for (int q = 0; q < 6; ++q) z[q] = (lane & (32 >> q)) ? -P : P;
  z[6] = z[7] = z[8] = 0.f;
#pragma unroll
  for (int r = 0; r < 8; ++r) {
    z[6] += (r & 4) ? -p[r] : p[r];
    z[7] += (r & 2) ? -p[r] : p[r];
    z[8] += (r & 1) ? -p[r] : p[r];
  }
#pragma unroll
  for (int m = 1; m < 64; m <<= 1) {
#pragma unroll
    for (int q = 0; q < NQ; ++q) z[q] += shx(z[q], m);
  }
  int ffw = flags[1], ffb = flags[2];
  float lg[NCLS], mx = -1e30f;
#pragma unroll
  for (int k = 0; k < NCLS; ++k) {
    float t = ld(fcb, k, ffb);
#pragma unroll
    for (int q = 0; q < NQ; ++q) t += z[q] * ld(fcw, k * NQ + q, ffw);
    lg[k] = t; mx = fmaxf(mx, t);
  }
  float se = 0.f;
#pragma unroll
  for (int k = 0; k < NCLS; ++k) se += expf(lg[k] - mx);
  float lse = mx + logf(se);
  if (lane < NCLS) out[(size_t)wid * NCLS + lane] = lg[lane] - lse;
}

extern "C" void kernel_launch(void* const* d_in, const int* in_sizes, int n_in,
                              void* d_out, int out_size, void* d_ws, size_t ws_size,
                              hipStream_t stream) {
  const void* x   = d_in[0];
  const void* rot = d_in[1];
  const void* crx = d_in[2];
  const void* fcw = d_in[3];
  const void* fcb = d_in[4];
  float* out = (float*)d_out;
  if (ws_size >= WS_NEED) {
    __hip_bfloat16* A  = (__hip_bfloat16*)((char*)d_ws + A_OFF);
    __hip_bfloat16* BT = (__hip_bfloat16*)((char*)d_ws + BT_OFF);
    float*          Zp = (float*)((char*)d_ws + ZP_OFF);
    prep_kernel<<<CIRC_BLKS + CAST_BLKS, 128, 0, stream>>>(x, rot, crx, A, BT);
    gemm_z_kernel<<<(B_TOT / 256) * (1024 / 256), 512, 0, stream>>>(
        (const unsigned short*)A, (const unsigned short*)BT, Zp);
    zred_kernel<<<B_TOT / 128, 128, 0, stream>>>(Zp, fcw, fcb, out);
  } else {
    qnn_kernel<<<(B_TOT * 64) / 256, 256, 0, stream>>>(x, rot, crx, fcw, fcb, out);
  }
}